// Round 8
// baseline (146.249 us; speedup 1.0000x reference)
//
#include <hip/hip_runtime.h>

// qpNet: h = x @ W^T + b ; z = max(-h, -1000). x:[B,5] f32, W:[5,5], b:[5].
// B = 4194304. 168 MB app traffic (84r+84w). Copy-rate floor ~27 us.
//
// R2:  80 B lane stride, one-shot      -> 57 us
// R3:  block LDS transpose + barrier   -> 50 us
// R5:  nt STORES @ 64B-stride layout   -> 82 us (WRITE 1.76x: nt forbade L2
//      from merging 16B partial-line fragments -- layout-specific failure!)
// R6:  wave-private LDS transpose      -> ~50 us
// R7:  R6 + reg prefetch               -> 51.4 us (VGPR=28: prefetch sunk)
// R9:  no-LDS, 80 B stride             -> 61 us
// R10: R7 + sched_barrier pin          -> 49.6 us
// R11: global_load_lds dbuf vmcnt(10)  -> 50.2 us (overlap guaranteed, flat)
// R12: shuffle kernel, no LDS          -> 53.4 us
//   => 5 disjoint structures all ~50 us: structure/depth/occupancy exonerated.
// R13: R10 + NONTEMPORAL LOADS         -> kernel <50 us (vanished below the
//      fills in top-5), dur_us 151.4->145.8 (-5.6). Cache-ALLOCATION traffic
//      was the structure-invariant cap. Fills' FETCH 14.5->8 confirms x no
//      longer populates L3.
// R14 (this): + NONTEMPORAL STORES. R5's blow-up was partial-line fragments;
//      here each wave store covers 16 COMPLETE 64B lines, so nt streams full
//      lines and skips L2/L3 write-allocate + eviction for 84 MB/dispatch --
//      same mechanism that just paid on the read side.
//      Fork (pre-committed): WRITE stays ~84 MB + time drops => keep.
//      WRITE >=1.3x or time regresses => revert to cached stores (R5 repeat).

#define BLOCK 256
#define WAVES_PER_BLOCK 4          // BLOCK / 64
#define F4_PER_TILE 320            // 64 lanes * 5 f4 = 1280 floats = 256 rows
#define TILES_PER_WAVE 4           // 4096 waves total = 1024 blocks

typedef float vf4 __attribute__((ext_vector_type(4)));

__global__ __launch_bounds__(BLOCK) void qpnet_kernel(
    const float* __restrict__ x,
    const float* __restrict__ W,
    const float* __restrict__ bfc,
    float* __restrict__ out,
    int total_f4)
{
    __shared__ __align__(16) float lds[BLOCK * 20];   // 20 KB: 5 KB per wave

    // 5x5 weights + bias. Uniform addresses -> compiler scalarizes (s_load).
    float w[5][5];
    float bias[5];
#pragma unroll
    for (int j = 0; j < 5; ++j) {
        bias[j] = bfc[j];
#pragma unroll
        for (int i = 0; i < 5; ++i) w[j][i] = W[j * 5 + i];
    }

    const int wave = threadIdx.x >> 6;
    const int lane = threadIdx.x & 63;
    float* __restrict__ wlds = &lds[wave * (64 * 20)];   // this wave's 1280 floats

    const int wave_id = blockIdx.x * WAVES_PER_BLOCK + wave;
    const int tb = wave_id * (F4_PER_TILE * TILES_PER_WAVE);  // f4 units; fits int
    if (tb >= total_f4) return;                               // exact division

    const vf4* __restrict__ xin  = reinterpret_cast<const vf4*>(x);
    vf4* __restrict__       zout = reinterpret_cast<vf4*>(out);

    // ---- prologue: tile 0 loads (lane-contiguous, full-line, NONTEMPORAL)
    vf4 r[5];
#pragma unroll
    for (int k = 0; k < 5; ++k)
        r[k] = __builtin_nontemporal_load(&xin[tb + k * 64 + lane]);

#pragma unroll
    for (int t = 0; t < TILES_PER_WAVE; ++t) {
        const int cur = tb + t * F4_PER_TILE;

        // ---- stage current tile: regs -> LDS (waits vmcnt on r's loads only;
        // older stores may still be outstanding).
#pragma unroll
        for (int k = 0; k < 5; ++k)
            *reinterpret_cast<vf4*>(&wlds[(k * 64 + lane) * 4]) = r[k];

        // ---- issue NEXT tile's loads NOW (nontemporal), pinned by
        // sched_barrier(0) so the scheduler cannot sink them below.
        vf4 rn[5];
        if (t + 1 < TILES_PER_WAVE) {
            const int nxt = cur + F4_PER_TILE;
#pragma unroll
            for (int k = 0; k < 5; ++k)
                rn[k] = __builtin_nontemporal_load(&xin[nxt + k * 64 + lane]);
        }
        __builtin_amdgcn_sched_barrier(0);

        // Intra-wave exchange: SIMD lockstep + in-order DS pipe; drain lgkm
        // and fence the compiler (no __syncthreads needed, wave-private LDS).
        asm volatile("s_waitcnt lgkmcnt(0)" ::: "memory");

        // ---- transposed read: own 20 consecutive floats = 4 complete rows
        // (word addr lane*20 + 4p: stride-20 f4 groups cover all 32 banks / 8 lanes)
        float v[20];
#pragma unroll
        for (int p = 0; p < 5; ++p)
            *reinterpret_cast<vf4*>(&v[4 * p]) =
                *reinterpret_cast<const vf4*>(&wlds[lane * 20 + 4 * p]);

        // ---- compute: 4 rows x (5x5 matvec + bias + clamp), in place
#pragma unroll
        for (int k = 0; k < 4; ++k) {
            float t0 = bias[0], t1 = bias[1], t2 = bias[2], t3 = bias[3], t4 = bias[4];
#pragma unroll
            for (int i = 0; i < 5; ++i) {
                const float xv = v[k * 5 + i];
                t0 = fmaf(xv, w[0][i], t0);
                t1 = fmaf(xv, w[1][i], t1);
                t2 = fmaf(xv, w[2][i], t2);
                t3 = fmaf(xv, w[3][i], t3);
                t4 = fmaf(xv, w[4][i], t4);
            }
            v[k * 5 + 0] = fmaxf(-t0, -1000.0f);
            v[k * 5 + 1] = fmaxf(-t1, -1000.0f);
            v[k * 5 + 2] = fmaxf(-t2, -1000.0f);
            v[k * 5 + 3] = fmaxf(-t3, -1000.0f);
            v[k * 5 + 4] = fmaxf(-t4, -1000.0f);
        }

        // ---- transposed write back to own region
#pragma unroll
        for (int p = 0; p < 5; ++p)
            *reinterpret_cast<vf4*>(&wlds[lane * 20 + 4 * p]) =
                *reinterpret_cast<const vf4*>(&v[4 * p]);
        asm volatile("s_waitcnt lgkmcnt(0)" ::: "memory");

        // ---- stage out: LDS -> lane-contiguous NONTEMPORAL global stores.
        // Each wave instr covers 16 complete 64B lines (full coverage), so nt
        // streams whole lines; skips L2/L3 write-allocate + later eviction.
#pragma unroll
        for (int k = 0; k < 5; ++k) {
            const vf4 val = *reinterpret_cast<const vf4*>(&wlds[(k * 64 + lane) * 4]);
            __builtin_nontemporal_store(val, &zout[cur + k * 64 + lane]);
        }

        // hand prefetch to next iteration (full unroll -> SSA rename, no movs)
        if (t + 1 < TILES_PER_WAVE) {
#pragma unroll
            for (int k = 0; k < 5; ++k) r[k] = rn[k];
        }
    }
}

extern "C" void kernel_launch(void* const* d_in, const int* in_sizes, int n_in,
                              void* d_out, int out_size, void* d_ws, size_t ws_size,
                              hipStream_t stream) {
    const float* x   = (const float*)d_in[0];   // [B,5]
    const float* W   = (const float*)d_in[1];   // [5,5]
    const float* bfc = (const float*)d_in[2];   // [5]
    float* out = (float*)d_out;                 // [B,5]

    int total_f4 = in_sizes[0] / 4;             // 5,242,880
    int f4_per_wave = F4_PER_TILE * TILES_PER_WAVE;                    // 1280
    int n_waves  = (total_f4 + f4_per_wave - 1) / f4_per_wave;         // 4096
    int grid     = (n_waves + WAVES_PER_BLOCK - 1) / WAVES_PER_BLOCK;  // 1024

    qpnet_kernel<<<grid, BLOCK, 0, stream>>>(x, W, bfc, out, total_f4);
}